// Round 6
// baseline (112.012 us; speedup 1.0000x reference)
//
#include <hip/hip_runtime.h>

// TransfPropModule — round-4 structure (prepacked per-lane gather, LDS-staged
// coalesced streams), with PLAIN stores instead of non-temporal.
//
// Evidence: FETCH_SIZE was 60.7 MB in rounds 1-4 regardless of NT hints, so
// NT buys nothing on the read side. The harness memset sustains 7.2 TB/s with
// plain stores; our NT writes (80% of our HBM bytes) are the one untested
// variable. A/B: NT removed, everything else identical to round 4.

typedef float f4 __attribute__((ext_vector_type(4)));

__global__ void __launch_bounds__(256)
prepack_kernel(const float* __restrict__ cw,
               const float* __restrict__ Rm,
               const float* __restrict__ tm,
               float* __restrict__ packed,
               int M)
{
    int i = blockIdx.x * 256 + threadIdx.x;   // element index into packed
    if (i >= M * 16) return;
    int r = i >> 4, j = i & 15;
    float v = 0.0f;
    if (j < 9)       v = Rm[r * 9 + j];
    else if (j < 12) v = tm[r * 3 + (j - 9)];
    else if (j == 12) v = cw[r];
    packed[i] = v;
}

__global__ void __launch_bounds__(256)
transf_prop_kernel(const float* __restrict__ x,
                   const float* __restrict__ pos,
                   const float* __restrict__ packed,
                   const int*   __restrict__ cidx,
                   float* __restrict__ Rp,
                   float* __restrict__ tp,
                   float* __restrict__ xo,
                   int n)
{
    __shared__ __align__(16) float s_pos[768];
    __shared__ __align__(16) float s_x[768];
    __shared__ __align__(16) float s_R[2304];
    __shared__ __align__(16) float s_t[768];
    __shared__ __align__(16) float s_o[768];

    const int t    = threadIdx.x;
    const int base = blockIdx.x * 256;

    if (base + 256 <= n) {
        // ---------- fast path: full block of 256 points ----------
        const int c = cidx[base + t];
        const f4* row = (const f4*)(packed + (size_t)c * 16);
        const f4 q0 = row[0];           // r0 r1 r2 r3
        const f4 q1 = row[1];           // r4 r5 r6 r7
        const f4 q2 = row[2];           // r8 t0 t1 t2
        const f4 q3 = row[3];           // w  -  -  -

        // coalesced float4 staging of pos/x (768 floats = 192 vec4 each)
        const f4* pos4 = (const f4*)(pos + (size_t)base * 3);
        const f4* x4   = (const f4*)(x   + (size_t)base * 3);
        if (t < 192) {
            ((f4*)s_pos)[t] = pos4[t];
            ((f4*)s_x)[t]   = x4[t];
        }
        __syncthreads();

        const float p0 = s_pos[t * 3 + 0];
        const float p1 = s_pos[t * 3 + 1];
        const float p2 = s_pos[t * 3 + 2];
        const float x0 = s_x[t * 3 + 0];
        const float x1 = s_x[t * 3 + 1];
        const float x2 = s_x[t * 3 + 2];

        const float pr0 = fmaf(q0.x, p0, fmaf(q0.y, p1, fmaf(q0.z, p2, q2.y)));
        const float pr1 = fmaf(q0.w, p0, fmaf(q1.x, p1, fmaf(q1.y, p2, q2.z)));
        const float pr2 = fmaf(q1.z, p0, fmaf(q1.w, p1, fmaf(q2.x, p2, q2.w)));
        const float w   = q3.x;
        const float omw = 1.0f - w;

        s_R[t * 9 + 0] = q0.x; s_R[t * 9 + 1] = q0.y; s_R[t * 9 + 2] = q0.z;
        s_R[t * 9 + 3] = q0.w; s_R[t * 9 + 4] = q1.x; s_R[t * 9 + 5] = q1.y;
        s_R[t * 9 + 6] = q1.z; s_R[t * 9 + 7] = q1.w; s_R[t * 9 + 8] = q2.x;
        s_t[t * 3 + 0] = q2.y;
        s_t[t * 3 + 1] = q2.z;
        s_t[t * 3 + 2] = q2.w;
        s_o[t * 3 + 0] = fmaf(x0, w, pr0 * omw);
        s_o[t * 3 + 1] = fmaf(x1, w, pr1 * omw);
        s_o[t * 3 + 2] = fmaf(x2, w, pr2 * omw);
        __syncthreads();

        // vectorized writeback (plain stores — A/B vs round 4's NT)
        f4* Rb4 = (f4*)(Rp + (size_t)base * 9);        // 2304 f = 576 vec4
        const f4* sR4 = (const f4*)s_R;
        Rb4[t]       = sR4[t];
        Rb4[t + 256] = sR4[t + 256];
        if (t < 64)
            Rb4[t + 512] = sR4[t + 512];

        f4* tb4 = (f4*)(tp + (size_t)base * 3);        // 192 vec4
        f4* ob4 = (f4*)(xo + (size_t)base * 3);
        if (t < 192) {
            tb4[t] = ((const f4*)s_t)[t];
            ob4[t] = ((const f4*)s_o)[t];
        }
    } else {
        // ---------- generic tail path (unused when n % 256 == 0) ----------
        const int m  = n - base;
        const int m3 = m * 3, m9 = m * 9;
        const float* posb = pos + (size_t)base * 3;
        const float* xb   = x   + (size_t)base * 3;
        for (int k = 0; k < 3; ++k) {
            int i = t + 256 * k;
            if (i < m3) { s_pos[i] = posb[i]; s_x[i] = xb[i]; }
        }
        __syncthreads();
        if (t < m) {
            const int c = cidx[base + t];
            const float* row = packed + (size_t)c * 16;
            float r[9];
            for (int j = 0; j < 9; ++j) r[j] = row[j];
            const float t0 = row[9], t1 = row[10], t2 = row[11];
            const float w  = row[12];
            const float p0 = s_pos[t*3], p1 = s_pos[t*3+1], p2 = s_pos[t*3+2];
            const float x0 = s_x[t*3],   x1 = s_x[t*3+1],   x2 = s_x[t*3+2];
            const float pr0 = fmaf(r[0], p0, fmaf(r[1], p1, fmaf(r[2], p2, t0)));
            const float pr1 = fmaf(r[3], p0, fmaf(r[4], p1, fmaf(r[5], p2, t1)));
            const float pr2 = fmaf(r[6], p0, fmaf(r[7], p1, fmaf(r[8], p2, t2)));
            const float omw = 1.0f - w;
            for (int j = 0; j < 9; ++j) s_R[t * 9 + j] = r[j];
            s_t[t*3] = t0; s_t[t*3+1] = t1; s_t[t*3+2] = t2;
            s_o[t*3]   = fmaf(x0, w, pr0 * omw);
            s_o[t*3+1] = fmaf(x1, w, pr1 * omw);
            s_o[t*3+2] = fmaf(x2, w, pr2 * omw);
        }
        __syncthreads();
        float* Rb = Rp + (size_t)base * 9;
        for (int k = 0; k < 9; ++k) {
            int i = t + 256 * k;
            if (i < m9) Rb[i] = s_R[i];
        }
        float* tb = tp + (size_t)base * 3;
        float* ob = xo + (size_t)base * 3;
        for (int k = 0; k < 3; ++k) {
            int i = t + 256 * k;
            if (i < m3) {
                tb[i] = s_t[i];
                ob[i] = s_o[i];
            }
        }
    }
}

extern "C" void kernel_launch(void* const* d_in, const int* in_sizes, int n_in,
                              void* d_out, int out_size, void* d_ws, size_t ws_size,
                              hipStream_t stream) {
    const float* x   = (const float*)d_in[0];
    const float* pos = (const float*)d_in[1];
    // d_in[2] = batch (unused by reference)
    const float* cw  = (const float*)d_in[3];
    const float* Rm  = (const float*)d_in[4];
    const float* tm  = (const float*)d_in[5];
    const int*  edge = (const int*)d_in[6];

    const int n = in_sizes[0] / 3;           // N points
    const int M = in_sizes[3];               // clusters (cluster_weights is [M,1])
    const int* cidx = edge + n;              // edge_index row 1 = cluster idx

    float* out = (float*)d_out;
    float* Rp = out;                          // [N,3,3]
    float* tp = out + (size_t)n * 9;          // [N,3]
    float* xo = out + (size_t)n * 12;         // [N,3]

    float* packed = (float*)d_ws;             // [M,16] floats = 1 MB

    const int block = 256;
    const int pgrid = (M * 16 + block - 1) / block;
    prepack_kernel<<<pgrid, block, 0, stream>>>(cw, Rm, tm, packed, M);

    const int grid = (n + block - 1) / block;
    transf_prop_kernel<<<grid, block, 0, stream>>>(x, pos, packed, cidx,
                                                   Rp, tp, xo, n);
}

// Round 7
// 63.008 us; speedup vs baseline: 1.7777x; 1.7777x over previous
//
#include <hip/hip_runtime.h>

// TransfPropModule — round-4 structure (prepacked per-lane gather, LDS-staged
// coalesced streams, NT stores) + LDS aliasing for occupancy.
//
// Round-6 lesson: NT stores are decisive (plain stores +77%). Round-4 best =
// 63.3 us at ~5.1 TB/s effective vs ~6.5 TB/s mixed ceiling. Last lever:
// occupancy. s_t aliases s_pos and s_o aliases s_x — thread t reads
// s_pos/s_x[3t..3t+2] then writes s_t/s_o[3t..3t+2]: same thread, same
// addresses, no barrier needed. LDS 21504 -> 15360 B => 8 blocks/CU
// (32 waves, the cap) instead of 7.

typedef float f4 __attribute__((ext_vector_type(4)));

__global__ void __launch_bounds__(256)
prepack_kernel(const float* __restrict__ cw,
               const float* __restrict__ Rm,
               const float* __restrict__ tm,
               float* __restrict__ packed,
               int M)
{
    int i = blockIdx.x * 256 + threadIdx.x;   // element index into packed
    if (i >= M * 16) return;
    int r = i >> 4, j = i & 15;
    float v = 0.0f;
    if (j < 9)       v = Rm[r * 9 + j];
    else if (j < 12) v = tm[r * 3 + (j - 9)];
    else if (j == 12) v = cw[r];
    packed[i] = v;
}

__global__ void __launch_bounds__(256)
transf_prop_kernel(const float* __restrict__ x,
                   const float* __restrict__ pos,
                   const float* __restrict__ packed,
                   const int*   __restrict__ cidx,
                   float* __restrict__ Rp,
                   float* __restrict__ tp,
                   float* __restrict__ xo,
                   int n)
{
    // s_pos/s_t and s_x/s_o alias (see header comment). s_R separate.
    __shared__ __align__(16) float s_a[768];    // pos, then t
    __shared__ __align__(16) float s_b[768];    // x,   then o
    __shared__ __align__(16) float s_R[2304];

    float* s_pos = s_a;  float* s_t = s_a;
    float* s_x   = s_b;  float* s_o = s_b;

    const int t    = threadIdx.x;
    const int base = blockIdx.x * 256;

    if (base + 256 <= n) {
        // ---------- fast path: full block of 256 points ----------
        const int c = cidx[base + t];
        const f4* row = (const f4*)(packed + (size_t)c * 16);
        const f4 q0 = row[0];           // r0 r1 r2 r3
        const f4 q1 = row[1];           // r4 r5 r6 r7
        const f4 q2 = row[2];           // r8 t0 t1 t2
        const f4 q3 = row[3];           // w  -  -  -

        // coalesced float4 staging of pos/x (768 floats = 192 vec4 each)
        const f4* pos4 = (const f4*)(pos + (size_t)base * 3);
        const f4* x4   = (const f4*)(x   + (size_t)base * 3);
        if (t < 192) {
            ((f4*)s_pos)[t] = pos4[t];
            ((f4*)s_x)[t]   = x4[t];
        }
        __syncthreads();

        const float p0 = s_pos[t * 3 + 0];
        const float p1 = s_pos[t * 3 + 1];
        const float p2 = s_pos[t * 3 + 2];
        const float x0 = s_x[t * 3 + 0];
        const float x1 = s_x[t * 3 + 1];
        const float x2 = s_x[t * 3 + 2];

        const float pr0 = fmaf(q0.x, p0, fmaf(q0.y, p1, fmaf(q0.z, p2, q2.y)));
        const float pr1 = fmaf(q0.w, p0, fmaf(q1.x, p1, fmaf(q1.y, p2, q2.z)));
        const float pr2 = fmaf(q1.z, p0, fmaf(q1.w, p1, fmaf(q2.x, p2, q2.w)));
        const float w   = q3.x;
        const float omw = 1.0f - w;

        s_R[t * 9 + 0] = q0.x; s_R[t * 9 + 1] = q0.y; s_R[t * 9 + 2] = q0.z;
        s_R[t * 9 + 3] = q0.w; s_R[t * 9 + 4] = q1.x; s_R[t * 9 + 5] = q1.y;
        s_R[t * 9 + 6] = q1.z; s_R[t * 9 + 7] = q1.w; s_R[t * 9 + 8] = q2.x;
        // overwrite own slots (same thread read them above — no barrier needed)
        s_t[t * 3 + 0] = q2.y;
        s_t[t * 3 + 1] = q2.z;
        s_t[t * 3 + 2] = q2.w;
        s_o[t * 3 + 0] = fmaf(x0, w, pr0 * omw);
        s_o[t * 3 + 1] = fmaf(x1, w, pr1 * omw);
        s_o[t * 3 + 2] = fmaf(x2, w, pr2 * omw);
        __syncthreads();

        // vectorized non-temporal writeback
        f4* Rb4 = (f4*)(Rp + (size_t)base * 9);        // 2304 f = 576 vec4
        const f4* sR4 = (const f4*)s_R;
        __builtin_nontemporal_store(sR4[t],       &Rb4[t]);
        __builtin_nontemporal_store(sR4[t + 256], &Rb4[t + 256]);
        if (t < 64)
            __builtin_nontemporal_store(sR4[t + 512], &Rb4[t + 512]);

        f4* tb4 = (f4*)(tp + (size_t)base * 3);        // 192 vec4
        f4* ob4 = (f4*)(xo + (size_t)base * 3);
        if (t < 192) {
            __builtin_nontemporal_store(((const f4*)s_t)[t], &tb4[t]);
            __builtin_nontemporal_store(((const f4*)s_o)[t], &ob4[t]);
        }
    } else {
        // ---------- generic tail path (unused when n % 256 == 0) ----------
        const int m  = n - base;
        const int m3 = m * 3, m9 = m * 9;
        const float* posb = pos + (size_t)base * 3;
        const float* xb   = x   + (size_t)base * 3;
        for (int k = 0; k < 3; ++k) {
            int i = t + 256 * k;
            if (i < m3) { s_pos[i] = posb[i]; s_x[i] = xb[i]; }
        }
        __syncthreads();
        float r[9], tv[3], ov[3];
        bool live = (t < m);
        if (live) {
            const int c = cidx[base + t];
            const float* rowp = packed + (size_t)c * 16;
            for (int j = 0; j < 9; ++j) r[j] = rowp[j];
            const float t0 = rowp[9], t1 = rowp[10], t2 = rowp[11];
            const float w  = rowp[12];
            const float p0 = s_pos[t*3], p1 = s_pos[t*3+1], p2 = s_pos[t*3+2];
            const float x0 = s_x[t*3],   x1 = s_x[t*3+1],   x2 = s_x[t*3+2];
            const float pr0 = fmaf(r[0], p0, fmaf(r[1], p1, fmaf(r[2], p2, t0)));
            const float pr1 = fmaf(r[3], p0, fmaf(r[4], p1, fmaf(r[5], p2, t1)));
            const float pr2 = fmaf(r[6], p0, fmaf(r[7], p1, fmaf(r[8], p2, t2)));
            const float omw = 1.0f - w;
            tv[0] = t0; tv[1] = t1; tv[2] = t2;
            ov[0] = fmaf(x0, w, pr0 * omw);
            ov[1] = fmaf(x1, w, pr1 * omw);
            ov[2] = fmaf(x2, w, pr2 * omw);
        }
        __syncthreads();   // all reads of s_pos/s_x done before overwrite
        if (live) {
            for (int j = 0; j < 9; ++j) s_R[t * 9 + j] = r[j];
            s_t[t*3] = tv[0]; s_t[t*3+1] = tv[1]; s_t[t*3+2] = tv[2];
            s_o[t*3] = ov[0]; s_o[t*3+1] = ov[1]; s_o[t*3+2] = ov[2];
        }
        __syncthreads();
        float* Rb = Rp + (size_t)base * 9;
        for (int k = 0; k < 9; ++k) {
            int i = t + 256 * k;
            if (i < m9) __builtin_nontemporal_store(s_R[i], &Rb[i]);
        }
        float* tb = tp + (size_t)base * 3;
        float* ob = xo + (size_t)base * 3;
        for (int k = 0; k < 3; ++k) {
            int i = t + 256 * k;
            if (i < m3) {
                __builtin_nontemporal_store(s_t[i], &tb[i]);
                __builtin_nontemporal_store(s_o[i], &ob[i]);
            }
        }
    }
}

extern "C" void kernel_launch(void* const* d_in, const int* in_sizes, int n_in,
                              void* d_out, int out_size, void* d_ws, size_t ws_size,
                              hipStream_t stream) {
    const float* x   = (const float*)d_in[0];
    const float* pos = (const float*)d_in[1];
    // d_in[2] = batch (unused by reference)
    const float* cw  = (const float*)d_in[3];
    const float* Rm  = (const float*)d_in[4];
    const float* tm  = (const float*)d_in[5];
    const int*  edge = (const int*)d_in[6];

    const int n = in_sizes[0] / 3;           // N points
    const int M = in_sizes[3];               // clusters (cluster_weights is [M,1])
    const int* cidx = edge + n;              // edge_index row 1 = cluster idx

    float* out = (float*)d_out;
    float* Rp = out;                          // [N,3,3]
    float* tp = out + (size_t)n * 9;          // [N,3]
    float* xo = out + (size_t)n * 12;         // [N,3]

    float* packed = (float*)d_ws;             // [M,16] floats = 1 MB

    const int block = 256;
    const int pgrid = (M * 16 + block - 1) / block;
    prepack_kernel<<<pgrid, block, 0, stream>>>(cw, Rm, tm, packed, M);

    const int grid = (n + block - 1) / block;
    transf_prop_kernel<<<grid, block, 0, stream>>>(x, pos, packed, cidx,
                                                   Rp, tp, xo, n);
}